// Round 4
// baseline (2283.124 us; speedup 1.0000x reference)
//
#include <hip/hip_runtime.h>
#include <hip/hip_bf16.h>

// ---------------------------------------------------------------------------
// RNN_20572893348005: 2-layer tanh RNN, B=64 T=1024 D=128 H=256, out [B,H,T]
// Dtype (bf16 vs f32) runtime-detected; compute f16 operands / fp32 accum.
//
// R4: MFMA scan. h_new = tanh(W_hh·h + xw): per WG 8 batches via
// mfma_f32_16x16x32_f16 (M=256 j, N=16 lanes w/ 8 used, K=256).
// W_hh A-fragments live in VGPRs (128 regs); h ping-pongs in LDS in
// B-fragment layout -> 8 fully-distributed ds_read_b128/wave/step
// (vs 128 broadcast reads/CU/step in R3 — the measured 1870cyc/step cost).
// Layers pipelined: one dispatch runs layer0 chunk s (blocks 0-7) and
// layer1 chunk s-1 (blocks 8-15) concurrently. Layer1 writes [b][t][j] f16;
// a small LDS transpose kernel produces out[b][j][t].
// ---------------------------------------------------------------------------

#define B_ 64
#define T_ 1024
#define D_ 128
#define H_ 256
#define NB 8   // batches per scan workgroup

typedef _Float16 half2_t __attribute__((ext_vector_type(2)));
typedef _Float16 half8_t __attribute__((ext_vector_type(8)));
typedef float    f32x4_t __attribute__((ext_vector_type(4)));

__device__ __forceinline__ float bf2f(unsigned short u) {
    union { unsigned int i; float f; } v;
    v.i = ((unsigned int)u) << 16;
    return v.f;
}

__device__ __forceinline__ unsigned int cvt2_bf16_to_f16(unsigned int u) {
    union { float f; unsigned int i; } a, b;
    a.i = u << 16;
    b.i = u & 0xFFFF0000u;
    union { _Float16 h[2]; unsigned int u; } r;
    r.h[0] = (_Float16)a.f;
    r.h[1] = (_Float16)b.f;
    return r.u;
}

__device__ __forceinline__ uint4 cvt8_bf16_to_f16(uint4 v) {
    uint4 r;
    r.x = cvt2_bf16_to_f16(v.x);
    r.y = cvt2_bf16_to_f16(v.y);
    r.z = cvt2_bf16_to_f16(v.z);
    r.w = cvt2_bf16_to_f16(v.w);
    return r;
}

__device__ __forceinline__ float dot2(unsigned int a, unsigned int b, float c) {
    union { unsigned int u; half2_t h; } ua, ub;
    ua.u = a; ub.u = b;
#if defined(__HIP_DEVICE_COMPILE__) && __has_builtin(__builtin_amdgcn_fdot2)
    return __builtin_amdgcn_fdot2(ua.h, ub.h, c, false);
#else
    return c + (float)ua.h.x * (float)ub.h.x + (float)ua.h.y * (float)ub.h.y;
#endif
}

// tanh(x) = 1 - 2/(exp(2x)+1); exp via v_exp_f32. NaN/inf-free for all finite x.
__device__ __forceinline__ float tanh_fast(float x) {
#if defined(__HIP_DEVICE_COMPILE__) && __has_builtin(__builtin_amdgcn_exp2f)
    float e = __builtin_amdgcn_exp2f(x * 2.885390081777927f);  // exp(2x)
#else
    float e = exp2f(x * 2.885390081777927f);
#endif
    return 1.f - 2.f / (e + 1.f);
}

// ---- dtype detection (bf16 weights have exponent field <= 122) -----------
__global__ void detect_dtype(const unsigned short* __restrict__ w, int* __restrict__ flag) {
    if (threadIdx.x == 0 && blockIdx.x == 0) {
        int f = 0;
        for (int i = 0; i < 512; ++i) {
            unsigned e = (w[i] >> 7) & 0xFF;
            if (e >= 127) f = 1;
        }
        *flag = f;
    }
}

// ---- prep: weights -> f16, bias sums -> f32, zero carries ----------------
__global__ void prep_w(const void* __restrict__ wih0, const void* __restrict__ whh0,
                       const void* __restrict__ bih0, const void* __restrict__ bhh0,
                       const void* __restrict__ wih1, const void* __restrict__ whh1,
                       const void* __restrict__ bih1, const void* __restrict__ bhh1,
                       _Float16* __restrict__ owih0, _Float16* __restrict__ owhh0,
                       _Float16* __restrict__ owih1, _Float16* __restrict__ owhh1,
                       float* __restrict__ obias0, float* __restrict__ obias1,
                       uint4* __restrict__ carries, const int* __restrict__ flag) {
    const bool f32 = (*flag != 0);
    int i = blockIdx.x * 256 + threadIdx.x;
    auto rd = [&](const void* p, int idx) -> float {
        return f32 ? ((const float*)p)[idx] : bf2f(((const unsigned short*)p)[idx]);
    };
    if (i < H_ * D_) owih0[i] = (_Float16)rd(wih0, i);
    if (i < H_ * H_) {
        owhh0[i] = (_Float16)rd(whh0, i);
        owih1[i] = (_Float16)rd(wih1, i);
        owhh1[i] = (_Float16)rd(whh1, i);
    }
    if (i < H_) {
        obias0[i] = rd(bih0, i) + rd(bhh0, i);
        obias1[i] = rd(bih1, i) + rd(bhh1, i);
    }
    if (i < (2 * B_ * H_) / 8) carries[i] = uint4{0, 0, 0, 0};
}

// ---- chunk projection (dot2): xw[m][j] = A_row(m).W[j] + bias[j] ---------
template <int K, bool SRCX>
__global__ __launch_bounds__(256, 1) void proj_chunk(const void* __restrict__ A,
                                                     const _Float16* __restrict__ W,
                                                     const float* __restrict__ bias,
                                                     _Float16* __restrict__ outx,
                                                     const int* __restrict__ flag,
                                                     int t0, int Tc) {
    constexpr int KW = K / 8;
    const int j = threadIdx.x;
    const long m0 = (long)blockIdx.x * 16;
    const bool f32 = SRCX && (*flag != 0);

    long arow0;
    if (SRCX) {
        long b = m0 / Tc;
        long tc0 = m0 - b * Tc;
        arow0 = (b * T_ + t0 + tc0) * (long)K;
    } else {
        arow0 = m0 * (long)K;
    }

    uint4 w[KW];
    const uint4* wp = (const uint4*)(W + (long)j * K);
#pragma unroll
    for (int i = 0; i < KW; ++i) w[i] = wp[i];

    __shared__ uint4 xt[16 * KW];
    for (int i = threadIdx.x; i < 16 * KW; i += 256) {
        int r = i / KW, c = i % KW;
        long off = arow0 + (long)r * K + (long)c * 8;
        if (SRCX) {
            if (f32) {
                const float* s = (const float*)A + off;
                union { _Float16 h[8]; uint4 u; } r8;
#pragma unroll
                for (int q = 0; q < 8; ++q) r8.h[q] = (_Float16)s[q];
                xt[i] = r8.u;
            } else {
                xt[i] = cvt8_bf16_to_f16(*(const uint4*)((const unsigned short*)A + off));
            }
        } else {
            xt[i] = *(const uint4*)((const _Float16*)A + off);
        }
    }
    __syncthreads();

    const float bb = bias[j];
#pragma unroll 1
    for (int r = 0; r < 16; ++r) {
        const uint4* xr = xt + r * KW;
        float a0 = 0.f, a1 = 0.f, a2 = 0.f, a3 = 0.f;
#pragma unroll
        for (int i = 0; i < KW; ++i) {
            uint4 h = xr[i];
            uint4 ww = w[i];
            a0 = dot2(ww.x, h.x, a0);
            a1 = dot2(ww.y, h.y, a1);
            a2 = dot2(ww.z, h.z, a2);
            a3 = dot2(ww.w, h.w, a3);
        }
        outx[(m0 + r) * H_ + j] = (_Float16)(((a0 + a1) + (a2 + a3)) + bb);
    }
}

// ---- fused MFMA scan ------------------------------------------------------
// grid = 16 blocks: 0-7 layer0 (batch groups), 8-15 layer1.
// Per WG: 8 batches, 256 threads (4 waves), wave w owns M-tiles w*4..w*4+3.
// A-frag (16x16x32 f16): lane(m=L&15, k=(L>>4)*8+r). B-frag: lane(n=L&15,
// k=(L>>4)*8+r). D: lane(n=L&15, j_local=(L>>4)*4+reg)  [verified layouts].
// h in LDS as [k>>3][n(16)][k&7] f16, double-buffered, 1 barrier/step.
__global__ __launch_bounds__(256, 1) void scan_mfma(
    const _Float16* __restrict__ xw0, const _Float16* __restrict__ whh0,
    _Float16* __restrict__ carry0, _Float16* __restrict__ hout0, int act0,
    const _Float16* __restrict__ xw1, const _Float16* __restrict__ whh1,
    _Float16* __restrict__ carry1, _Float16* __restrict__ hout1, int act1,
    int Tc) {
    const int layer = blockIdx.x >> 3;
    const int g = blockIdx.x & 7;
    if (layer == 0 && !act0) return;
    if (layer == 1 && !act1) return;
    const _Float16* xw  = layer ? xw1  : xw0;
    const _Float16* whh = layer ? whh1 : whh0;
    _Float16* carry = layer ? carry1 : carry0;
    _Float16* hout  = layer ? hout1 : hout0;

    const int tid = threadIdx.x;
    const int w = tid >> 6, L = tid & 63;
    const int q = L >> 4, n = L & 15;

    // W_hh A-fragments -> VGPRs (4 M-tiles x 8 K-tiles x 8 f16 = 128 VGPRs)
    half8_t a[4][8];
#pragma unroll
    for (int mi = 0; mi < 4; ++mi) {
        int m = (w * 4 + mi) * 16 + n;
#pragma unroll
        for (int kt = 0; kt < 8; ++kt)
            a[mi][kt] = *(const half8_t*)(whh + m * H_ + kt * 32 + q * 8);
    }

    __shared__ _Float16 hB[2][32 * 16 * 8];  // [oct=k>>3][n][k&7]
    for (int nn = 0; nn < 16; ++nn) {
        float v = (nn < NB) ? (float)carry[(g * NB + nn) * H_ + tid] : 0.f;
        hB[0][((tid >> 3) * 16 + nn) * 8 + (tid & 7)] = (_Float16)v;
    }
    __syncthreads();

    const int j0q = q * 4;
    for (int t = 0; t < Tc; ++t) {
        // prefetch xw (consumed after MFMAs; latency hidden by matrix pipe)
        uint2 xwv[4] = {uint2{0,0}, uint2{0,0}, uint2{0,0}, uint2{0,0}};
        if (n < NB) {
            const _Float16* xp = xw + ((long)(g * NB + n) * Tc + t) * H_;
#pragma unroll
            for (int mi = 0; mi < 4; ++mi)
                xwv[mi] = *(const uint2*)(xp + (w * 4 + mi) * 16 + j0q);
        }
        // B fragments: 8 distributed ds_read_b128
        const _Float16* hb = hB[t & 1];
        half8_t bf[8];
#pragma unroll
        for (int kt = 0; kt < 8; ++kt)
            bf[kt] = *(const half8_t*)(hb + ((kt * 4 + q) * 16 + n) * 8);

        f32x4_t acc[4];
#pragma unroll
        for (int mi = 0; mi < 4; ++mi) acc[mi] = (f32x4_t){0.f, 0.f, 0.f, 0.f};
#pragma unroll
        for (int kt = 0; kt < 8; ++kt) {
#pragma unroll
            for (int mi = 0; mi < 4; ++mi)
                acc[mi] = __builtin_amdgcn_mfma_f32_16x16x32_f16(a[mi][kt], bf[kt], acc[mi], 0, 0, 0);
        }

        _Float16* hw = hB[(t + 1) & 1];
#pragma unroll
        for (int mi = 0; mi < 4; ++mi) {
            int j0 = (w * 4 + mi) * 16 + j0q;
            union { _Float16 h[4]; uint2 u; } pk;
            const _Float16* xh = (const _Float16*)&xwv[mi];
#pragma unroll
            for (int r = 0; r < 4; ++r)
                pk.h[r] = (_Float16)tanh_fast(acc[mi][r] + (float)xh[r]);
            *(uint2*)(hw + ((j0 >> 3) * 16 + n) * 8 + (j0 & 7)) = pk.u;
            if (n < NB)
                *(uint2*)(hout + ((long)(g * NB + n) * Tc + t) * H_ + j0) = pk.u;
        }
        __syncthreads();
    }

    const _Float16* hf = hB[Tc & 1];
    for (int nn = 0; nn < NB; ++nn)
        carry[(g * NB + nn) * H_ + tid] = hf[((tid >> 3) * 16 + nn) * 8 + (tid & 7)];
}

// ---- transpose: ho1[b][t][j] f16 -> out[b][j][t0+t] (bf16|f32) -----------
#define TSTR 68  // f16 stride: 136B rows -> 8B-aligned b64 writes, ~4-way reads
__global__ __launch_bounds__(256) void transpose_out(const _Float16* __restrict__ hsrc,
                                                     void* __restrict__ out,
                                                     const int* __restrict__ flag,
                                                     int t0, int Tc) {
    const bool f32o = (*flag != 0);
    const int ntt = Tc >> 6;
    int bx = blockIdx.x;
    int b  = bx / (ntt * 4);
    int r  = bx % (ntt * 4);
    int tt = r >> 2, jt = r & 3;
    __shared__ _Float16 tile[64 * TSTR];
    int tid = threadIdx.x;
#pragma unroll
    for (int p = 0; p < 2; ++p) {
        int lin = p * 256 + tid;
        int t = lin >> 3, c = lin & 7;
        uint4 v = *(const uint4*)(hsrc + ((long)b * Tc + tt * 64 + t) * H_ + jt * 64 + c * 8);
        *(uint2*)(tile + t * TSTR + c * 8)     = uint2{v.x, v.y};
        *(uint2*)(tile + t * TSTR + c * 8 + 4) = uint2{v.z, v.w};
    }
    __syncthreads();
    int t = tid & 63, jl = tid >> 6;
#pragma unroll
    for (int p = 0; p < 16; ++p) {
        int j = p * 4 + jl;
        float v = (float)tile[t * TSTR + j];
        long oi = ((long)b * H_ + jt * 64 + j) * T_ + t0 + tt * 64 + t;
        if (f32o) ((float*)out)[oi] = v;
        else      ((__hip_bfloat16*)out)[oi] = __float2bfloat16(v);
    }
}

// ---------------------------------------------------------------------------
extern "C" void kernel_launch(void* const* d_in, const int* in_sizes, int n_in,
                              void* d_out, int out_size, void* d_ws, size_t ws_size,
                              hipStream_t stream) {
    const void* x    = d_in[0];
    const void* wih0 = d_in[1];
    const void* whh0 = d_in[2];
    const void* bih0 = d_in[3];
    const void* bhh0 = d_in[4];
    const void* wih1 = d_in[5];
    const void* whh1 = d_in[6];
    const void* bih1 = d_in[7];
    const void* bhh1 = d_in[8];
    (void)in_sizes; (void)n_in; (void)out_size;

    char* ws = (char*)d_ws;
    size_t off = 0;
    auto alloc = [&](size_t bytes) -> void* {
        void* p = ws + off;
        off += (bytes + 255) & ~(size_t)255;
        return p;
    };

    int*      flag    = (int*)alloc(256);
    _Float16* wih0_16 = (_Float16*)alloc((size_t)H_ * D_ * 2);
    _Float16* whh0_16 = (_Float16*)alloc((size_t)H_ * H_ * 2);
    _Float16* wih1_16 = (_Float16*)alloc((size_t)H_ * H_ * 2);
    _Float16* whh1_16 = (_Float16*)alloc((size_t)H_ * H_ * 2);
    float*    bias0   = (float*)alloc(H_ * 4);
    float*    bias1   = (float*)alloc(H_ * 4);
    _Float16* carry0  = (_Float16*)alloc((size_t)B_ * H_ * 2);
    _Float16* carry1  = (_Float16*)alloc((size_t)B_ * H_ * 2);
    size_t fixed = off;

    // 4 chunk buffers: xw0c, xw1c, hbufA, hbufB (each B*Tc*H f16)
    int Tc = 256;
    while (Tc > 32 && fixed + 4 * ((size_t)B_ * Tc * H_ * 2 + 256) > ws_size) Tc >>= 1;
    _Float16* xw0c = (_Float16*)alloc((size_t)B_ * Tc * H_ * 2);
    _Float16* xw1c = (_Float16*)alloc((size_t)B_ * Tc * H_ * 2);
    _Float16* hbuf[2];
    hbuf[0] = (_Float16*)alloc((size_t)B_ * Tc * H_ * 2);
    hbuf[1] = (_Float16*)alloc((size_t)B_ * Tc * H_ * 2);

    detect_dtype<<<1, 64, 0, stream>>>((const unsigned short*)whh0, flag);
    prep_w<<<(H_ * H_ + 255) / 256, 256, 0, stream>>>(
        wih0, whh0, bih0, bhh0, wih1, whh1, bih1, bhh1,
        wih0_16, whh0_16, wih1_16, whh1_16, bias0, bias1, (uint4*)carry0, flag);

    const int nproj = (B_ * Tc) / 16;
    const int nc = T_ / Tc;
    const int ntrans = B_ * (Tc / 64) * 4;
    // stage s: proj0(s) ; proj1(s-1) ; [scan0(s) || scan1(s-1)] ; transpose(s-1)
    for (int s = 0; s <= nc; ++s) {
        if (s < nc)
            proj_chunk<D_, true><<<nproj, 256, 0, stream>>>(x, wih0_16, bias0, xw0c, flag, s * Tc, Tc);
        if (s >= 1)
            proj_chunk<H_, false><<<nproj, 256, 0, stream>>>(hbuf[(s - 1) & 1], wih1_16, bias1, xw1c, flag, 0, Tc);
        scan_mfma<<<16, 256, 0, stream>>>(
            xw0c, whh0_16, carry0, hbuf[s & 1], (s < nc) ? 1 : 0,
            xw1c, whh1_16, carry1, hbuf[(s - 1) & 1], (s >= 1) ? 1 : 0, Tc);
        if (s >= 1)
            transpose_out<<<ntrans, 256, 0, stream>>>(hbuf[(s - 1) & 1], d_out, flag, (s - 1) * Tc, Tc);
    }
}

// Round 5
// 2171.049 us; speedup vs baseline: 1.0516x; 1.0516x over previous
//
#include <hip/hip_runtime.h>
#include <hip/hip_bf16.h>

// ---------------------------------------------------------------------------
// RNN_20572893348005: 2-layer tanh RNN, B=64 T=1024 D=128 H=256, out [B,H,T]
// Dtype (bf16 vs f32) runtime-detected; compute f16 operands / fp32 accum.
//
// R5: MFMA scan, de-stalled. Per WG 16 batches (full MFMA N), 4 WGs/layer,
// layers pipelined in one dispatch (grid 8). Per step:
//   - B-frags (h) from LDS (8 ds_read_b128, double-buffered)
//   - xw for step t+1 prefetched into regs (consumed next step -> latency hid)
//   - 32 mfma_f32_16x16x32_f16 per wave (W_hh A-frags resident in 128 VGPRs)
//   - tanh (exp2-based), pack f16, ds_write next h, global hout stores
//   - raw `s_waitcnt lgkmcnt(0); s_barrier` -> NO vmcnt drain per step
//     (hout stores have no in-kernel consumer; dispatch-end flush suffices)
// ---------------------------------------------------------------------------

#define B_ 64
#define T_ 1024
#define D_ 128
#define H_ 256
#define NB 16  // batches per scan workgroup (fills MFMA N dim)

typedef _Float16 half2_t __attribute__((ext_vector_type(2)));
typedef _Float16 half8_t __attribute__((ext_vector_type(8)));
typedef float    f32x4_t __attribute__((ext_vector_type(4)));

__device__ __forceinline__ float bf2f(unsigned short u) {
    union { unsigned int i; float f; } v;
    v.i = ((unsigned int)u) << 16;
    return v.f;
}

__device__ __forceinline__ unsigned int cvt2_bf16_to_f16(unsigned int u) {
    union { float f; unsigned int i; } a, b;
    a.i = u << 16;
    b.i = u & 0xFFFF0000u;
    union { _Float16 h[2]; unsigned int u; } r;
    r.h[0] = (_Float16)a.f;
    r.h[1] = (_Float16)b.f;
    return r.u;
}

__device__ __forceinline__ uint4 cvt8_bf16_to_f16(uint4 v) {
    uint4 r;
    r.x = cvt2_bf16_to_f16(v.x);
    r.y = cvt2_bf16_to_f16(v.y);
    r.z = cvt2_bf16_to_f16(v.z);
    r.w = cvt2_bf16_to_f16(v.w);
    return r;
}

__device__ __forceinline__ float dot2(unsigned int a, unsigned int b, float c) {
    union { unsigned int u; half2_t h; } ua, ub;
    ua.u = a; ub.u = b;
#if defined(__HIP_DEVICE_COMPILE__) && __has_builtin(__builtin_amdgcn_fdot2)
    return __builtin_amdgcn_fdot2(ua.h, ub.h, c, false);
#else
    return c + (float)ua.h.x * (float)ub.h.x + (float)ua.h.y * (float)ub.h.y;
#endif
}

// tanh(x) = 1 - 2/(exp(2x)+1); finite for all finite x (inf -> 1).
__device__ __forceinline__ float tanh_fast(float x) {
#if defined(__HIP_DEVICE_COMPILE__) && __has_builtin(__builtin_amdgcn_exp2f)
    float e = __builtin_amdgcn_exp2f(x * 2.885390081777927f);  // exp(2x)
#else
    float e = exp2f(x * 2.885390081777927f);
#endif
    return 1.f - 2.f / (e + 1.f);
}

// LDS-only workgroup barrier: waits ds ops, leaves global loads/stores in
// flight (avoids the per-step vmcnt(0) drain __syncthreads would emit).
__device__ __forceinline__ void wg_barrier_lds() {
    __asm__ volatile("s_waitcnt lgkmcnt(0)\n\ts_barrier" ::: "memory");
}

// ---- dtype detection (bf16 weights have exponent field <= 122) -----------
__global__ void detect_dtype(const unsigned short* __restrict__ w, int* __restrict__ flag) {
    if (threadIdx.x == 0 && blockIdx.x == 0) {
        int f = 0;
        for (int i = 0; i < 512; ++i) {
            unsigned e = (w[i] >> 7) & 0xFF;
            if (e >= 127) f = 1;
        }
        *flag = f;
    }
}

// ---- prep: weights -> f16, bias sums -> f32, zero carries ----------------
__global__ void prep_w(const void* __restrict__ wih0, const void* __restrict__ whh0,
                       const void* __restrict__ bih0, const void* __restrict__ bhh0,
                       const void* __restrict__ wih1, const void* __restrict__ whh1,
                       const void* __restrict__ bih1, const void* __restrict__ bhh1,
                       _Float16* __restrict__ owih0, _Float16* __restrict__ owhh0,
                       _Float16* __restrict__ owih1, _Float16* __restrict__ owhh1,
                       float* __restrict__ obias0, float* __restrict__ obias1,
                       uint4* __restrict__ carries, const int* __restrict__ flag) {
    const bool f32 = (*flag != 0);
    int i = blockIdx.x * 256 + threadIdx.x;
    auto rd = [&](const void* p, int idx) -> float {
        return f32 ? ((const float*)p)[idx] : bf2f(((const unsigned short*)p)[idx]);
    };
    if (i < H_ * D_) owih0[i] = (_Float16)rd(wih0, i);
    if (i < H_ * H_) {
        owhh0[i] = (_Float16)rd(whh0, i);
        owih1[i] = (_Float16)rd(wih1, i);
        owhh1[i] = (_Float16)rd(whh1, i);
    }
    if (i < H_) {
        obias0[i] = rd(bih0, i) + rd(bhh0, i);
        obias1[i] = rd(bih1, i) + rd(bhh1, i);
    }
    if (i < (2 * B_ * H_) / 8) carries[i] = uint4{0, 0, 0, 0};
}

// ---- chunk projection (dot2): xw[m][j] = A_row(m).W[j] + bias[j] ---------
template <int K, bool SRCX>
__global__ __launch_bounds__(256, 1) void proj_chunk(const void* __restrict__ A,
                                                     const _Float16* __restrict__ W,
                                                     const float* __restrict__ bias,
                                                     _Float16* __restrict__ outx,
                                                     const int* __restrict__ flag,
                                                     int t0, int Tc) {
    constexpr int KW = K / 8;
    const int j = threadIdx.x;
    const long m0 = (long)blockIdx.x * 16;
    const bool f32 = SRCX && (*flag != 0);

    long arow0;
    if (SRCX) {
        long b = m0 / Tc;
        long tc0 = m0 - b * Tc;
        arow0 = (b * T_ + t0 + tc0) * (long)K;
    } else {
        arow0 = m0 * (long)K;
    }

    uint4 w[KW];
    const uint4* wp = (const uint4*)(W + (long)j * K);
#pragma unroll
    for (int i = 0; i < KW; ++i) w[i] = wp[i];

    __shared__ uint4 xt[16 * KW];
    for (int i = threadIdx.x; i < 16 * KW; i += 256) {
        int r = i / KW, c = i % KW;
        long off = arow0 + (long)r * K + (long)c * 8;
        if (SRCX) {
            if (f32) {
                const float* s = (const float*)A + off;
                union { _Float16 h[8]; uint4 u; } r8;
#pragma unroll
                for (int q = 0; q < 8; ++q) r8.h[q] = (_Float16)s[q];
                xt[i] = r8.u;
            } else {
                xt[i] = cvt8_bf16_to_f16(*(const uint4*)((const unsigned short*)A + off));
            }
        } else {
            xt[i] = *(const uint4*)((const _Float16*)A + off);
        }
    }
    __syncthreads();

    const float bb = bias[j];
#pragma unroll 1
    for (int r = 0; r < 16; ++r) {
        const uint4* xr = xt + r * KW;
        float a0 = 0.f, a1 = 0.f, a2 = 0.f, a3 = 0.f;
#pragma unroll
        for (int i = 0; i < KW; ++i) {
            uint4 h = xr[i];
            uint4 ww = w[i];
            a0 = dot2(ww.x, h.x, a0);
            a1 = dot2(ww.y, h.y, a1);
            a2 = dot2(ww.z, h.z, a2);
            a3 = dot2(ww.w, h.w, a3);
        }
        outx[(m0 + r) * H_ + j] = (_Float16)(((a0 + a1) + (a2 + a3)) + bb);
    }
}

// ---- fused MFMA scan ------------------------------------------------------
// grid = 8: blocks 0-3 layer0 (batch groups of 16), 4-7 layer1.
// Wave w owns M-tiles w*4..w*4+3. A-frag lane(m=L&15, k=(L>>4)*8+r);
// B-frag lane(n=L&15, k=(L>>4)*8+r); D lane(n=L&15, j=(L>>4)*4+reg).
// h in LDS [k>>3][n(16)][k&7] f16, double-buffered, 1 LDS-barrier/step.
__global__ __launch_bounds__(256, 1) void scan_mfma(
    const _Float16* __restrict__ xw0, const _Float16* __restrict__ whh0,
    _Float16* __restrict__ carry0, _Float16* __restrict__ hout0, int act0,
    const _Float16* __restrict__ xw1, const _Float16* __restrict__ whh1,
    _Float16* __restrict__ carry1, _Float16* __restrict__ hout1, int act1,
    int Tc) {
    const int layer = blockIdx.x >> 2;
    const int g = blockIdx.x & 3;
    if (layer == 0 && !act0) return;
    if (layer == 1 && !act1) return;
    const _Float16* xw  = layer ? xw1  : xw0;
    const _Float16* whh = layer ? whh1 : whh0;
    _Float16* carry = layer ? carry1 : carry0;
    _Float16* hout  = layer ? hout1 : hout0;

    const int tid = threadIdx.x;
    const int w = tid >> 6, L = tid & 63;
    const int q = L >> 4, n = L & 15;
    const int j0q = q * 4;

    // W_hh A-fragments -> VGPRs (4 M-tiles x 8 K-tiles x 8 f16 = 128 VGPRs)
    half8_t a[4][8];
#pragma unroll
    for (int mi = 0; mi < 4; ++mi) {
        int m = (w * 4 + mi) * 16 + n;
#pragma unroll
        for (int kt = 0; kt < 8; ++kt)
            a[mi][kt] = *(const half8_t*)(whh + m * H_ + kt * 32 + q * 8);
    }

    __shared__ _Float16 hB[2][32 * 16 * 8];  // [oct=k>>3][n][k&7]
    for (int nn = 0; nn < NB; ++nn)
        hB[0][((tid >> 3) * 16 + nn) * 8 + (tid & 7)] = carry[(g * NB + nn) * H_ + tid];

    // xw row for this lane's batch n
    const _Float16* xp = xw + (long)(g * NB + n) * Tc * H_;
    auto ldxw = [&](int t, uint2* dst) {
        const _Float16* p = xp + (long)t * H_;
#pragma unroll
        for (int mi = 0; mi < 4; ++mi)
            dst[mi] = *(const uint2*)(p + (w * 4 + mi) * 16 + j0q);
    };

    uint2 xwv[4];
    ldxw(0, xwv);  // step-0 operand
    __syncthreads();

    for (int t = 0; t < Tc; ++t) {
        // B fragments: 8 distributed ds_read_b128
        const _Float16* hb = hB[t & 1];
        half8_t bf[8];
#pragma unroll
        for (int kt = 0; kt < 8; ++kt)
            bf[kt] = *(const half8_t*)(hb + ((kt * 4 + q) * 16 + n) * 8);

        // prefetch xw for next step (consumed after a full step -> hidden)
        uint2 xwn[4];
        ldxw((t + 1 < Tc) ? t + 1 : t, xwn);

        f32x4_t acc[4];
#pragma unroll
        for (int mi = 0; mi < 4; ++mi) acc[mi] = (f32x4_t){0.f, 0.f, 0.f, 0.f};
#pragma unroll
        for (int kt = 0; kt < 8; ++kt) {
#pragma unroll
            for (int mi = 0; mi < 4; ++mi)
                acc[mi] = __builtin_amdgcn_mfma_f32_16x16x32_f16(a[mi][kt], bf[kt], acc[mi], 0, 0, 0);
        }

        _Float16* hw = hB[(t + 1) & 1];
#pragma unroll
        for (int mi = 0; mi < 4; ++mi) {
            int j0 = (w * 4 + mi) * 16 + j0q;
            union { _Float16 h[4]; uint2 u; } pk;
            const _Float16* xh = (const _Float16*)&xwv[mi];
#pragma unroll
            for (int r = 0; r < 4; ++r)
                pk.h[r] = (_Float16)tanh_fast(acc[mi][r] + (float)xh[r]);
            *(uint2*)(hw + ((j0 >> 3) * 16 + n) * 8 + (j0 & 7)) = pk.u;
            *(uint2*)(hout + ((long)(g * NB + n) * Tc + t) * H_ + j0) = pk.u;  // no drain
        }
#pragma unroll
        for (int mi = 0; mi < 4; ++mi) xwv[mi] = xwn[mi];

        wg_barrier_lds();  // lgkmcnt(0) + s_barrier only
    }

    const _Float16* hf = hB[Tc & 1];
    for (int nn = 0; nn < NB; ++nn)
        carry[(g * NB + nn) * H_ + tid] = hf[((tid >> 3) * 16 + nn) * 8 + (tid & 7)];
}

// ---- transpose: ho1[b][t][j] f16 -> out[b][j][t0+t] (bf16|f32) -----------
#define TSTR 68  // f16 stride: 136B rows -> 8B-aligned b64 writes
__global__ __launch_bounds__(256) void transpose_out(const _Float16* __restrict__ hsrc,
                                                     void* __restrict__ out,
                                                     const int* __restrict__ flag,
                                                     int t0, int Tc) {
    const bool f32o = (*flag != 0);
    const int ntt = Tc >> 6;
    int bx = blockIdx.x;
    int b  = bx / (ntt * 4);
    int r  = bx % (ntt * 4);
    int tt = r >> 2, jt = r & 3;
    __shared__ _Float16 tile[64 * TSTR];
    int tid = threadIdx.x;
#pragma unroll
    for (int p = 0; p < 2; ++p) {
        int lin = p * 256 + tid;
        int t = lin >> 3, c = lin & 7;
        uint4 v = *(const uint4*)(hsrc + ((long)b * Tc + tt * 64 + t) * H_ + jt * 64 + c * 8);
        *(uint2*)(tile + t * TSTR + c * 8)     = uint2{v.x, v.y};
        *(uint2*)(tile + t * TSTR + c * 8 + 4) = uint2{v.z, v.w};
    }
    __syncthreads();
    int t = tid & 63, jl = tid >> 6;
#pragma unroll
    for (int p = 0; p < 16; ++p) {
        int j = p * 4 + jl;
        float v = (float)tile[t * TSTR + j];
        long oi = ((long)b * H_ + jt * 64 + j) * T_ + t0 + tt * 64 + t;
        if (f32o) ((float*)out)[oi] = v;
        else      ((__hip_bfloat16*)out)[oi] = __float2bfloat16(v);
    }
}

// ---------------------------------------------------------------------------
extern "C" void kernel_launch(void* const* d_in, const int* in_sizes, int n_in,
                              void* d_out, int out_size, void* d_ws, size_t ws_size,
                              hipStream_t stream) {
    const void* x    = d_in[0];
    const void* wih0 = d_in[1];
    const void* whh0 = d_in[2];
    const void* bih0 = d_in[3];
    const void* bhh0 = d_in[4];
    const void* wih1 = d_in[5];
    const void* whh1 = d_in[6];
    const void* bih1 = d_in[7];
    const void* bhh1 = d_in[8];
    (void)in_sizes; (void)n_in; (void)out_size;

    char* ws = (char*)d_ws;
    size_t off = 0;
    auto alloc = [&](size_t bytes) -> void* {
        void* p = ws + off;
        off += (bytes + 255) & ~(size_t)255;
        return p;
    };

    int*      flag    = (int*)alloc(256);
    _Float16* wih0_16 = (_Float16*)alloc((size_t)H_ * D_ * 2);
    _Float16* whh0_16 = (_Float16*)alloc((size_t)H_ * H_ * 2);
    _Float16* wih1_16 = (_Float16*)alloc((size_t)H_ * H_ * 2);
    _Float16* whh1_16 = (_Float16*)alloc((size_t)H_ * H_ * 2);
    float*    bias0   = (float*)alloc(H_ * 4);
    float*    bias1   = (float*)alloc(H_ * 4);
    _Float16* carry0  = (_Float16*)alloc((size_t)B_ * H_ * 2);
    _Float16* carry1  = (_Float16*)alloc((size_t)B_ * H_ * 2);
    size_t fixed = off;

    // 4 chunk buffers: xw0c, xw1c, hbufA, hbufB (each B*Tc*H f16)
    int Tc = 256;
    while (Tc > 32 && fixed + 4 * ((size_t)B_ * Tc * H_ * 2 + 256) > ws_size) Tc >>= 1;
    _Float16* xw0c = (_Float16*)alloc((size_t)B_ * Tc * H_ * 2);
    _Float16* xw1c = (_Float16*)alloc((size_t)B_ * Tc * H_ * 2);
    _Float16* hbuf[2];
    hbuf[0] = (_Float16*)alloc((size_t)B_ * Tc * H_ * 2);
    hbuf[1] = (_Float16*)alloc((size_t)B_ * Tc * H_ * 2);

    detect_dtype<<<1, 64, 0, stream>>>((const unsigned short*)whh0, flag);
    prep_w<<<(H_ * H_ + 255) / 256, 256, 0, stream>>>(
        wih0, whh0, bih0, bhh0, wih1, whh1, bih1, bhh1,
        wih0_16, whh0_16, wih1_16, whh1_16, bias0, bias1, (uint4*)carry0, flag);

    const int nproj = (B_ * Tc) / 16;
    const int nc = T_ / Tc;
    const int ntrans = B_ * (Tc / 64) * 4;
    // stage s: proj0(s) ; proj1(s-1) ; [scan0(s) || scan1(s-1)] ; transpose(s-1)
    for (int s = 0; s <= nc; ++s) {
        if (s < nc)
            proj_chunk<D_, true><<<nproj, 256, 0, stream>>>(x, wih0_16, bias0, xw0c, flag, s * Tc, Tc);
        if (s >= 1)
            proj_chunk<H_, false><<<nproj, 256, 0, stream>>>(hbuf[(s - 1) & 1], wih1_16, bias1, xw1c, flag, 0, Tc);
        scan_mfma<<<8, 256, 0, stream>>>(
            xw0c, whh0_16, carry0, hbuf[s & 1], (s < nc) ? 1 : 0,
            xw1c, whh1_16, carry1, hbuf[(s - 1) & 1], (s >= 1) ? 1 : 0, Tc);
        if (s >= 1)
            transpose_out<<<ntrans, 256, 0, stream>>>(hbuf[(s - 1) & 1], d_out, flag, (s - 1) * Tc, Tc);
    }
}

// Round 7
// 2115.708 us; speedup vs baseline: 1.0791x; 1.0262x over previous
//
#include <hip/hip_runtime.h>
#include <hip/hip_bf16.h>

// ---------------------------------------------------------------------------
// RNN_20572893348005: 2-layer tanh RNN, B=64 T=1024 D=128 H=256, out [B,H,T]
// Dtype (bf16 vs f32) runtime-detected; compute f16 operands / fp32 accum.
//
// R7 == R6 with the cvt_pkrtz type fixed:
//  - xw reads: 2-step register lookahead, ping-pong sets, no copies (no
//    same-step vmcnt wait); xw stored SWIZZLED so each lane's 16 values are
//    one contiguous 32B chunk (2x dwordx4).
//  - 8 independent MFMA acc chains (depth 4) instead of 4 chains (depth 8).
//  - activation: exp2-based tanh, v_cvt_pkrtz packing.
//  - lgkmcnt-only barrier per step (global stores never drained in-loop).
// ---------------------------------------------------------------------------

#define B_ 64
#define T_ 1024
#define D_ 128
#define H_ 256
#define NB 16  // batches per scan workgroup (fills MFMA N dim)

typedef _Float16 half2_t __attribute__((ext_vector_type(2)));
typedef __fp16   fp16x2_t __attribute__((ext_vector_type(2)));
typedef _Float16 half8_t __attribute__((ext_vector_type(8)));
typedef float    f32x4_t __attribute__((ext_vector_type(4)));

__device__ __forceinline__ float bf2f(unsigned short u) {
    union { unsigned int i; float f; } v;
    v.i = ((unsigned int)u) << 16;
    return v.f;
}

__device__ __forceinline__ unsigned int cvt2_bf16_to_f16(unsigned int u) {
    union { float f; unsigned int i; } a, b;
    a.i = u << 16;
    b.i = u & 0xFFFF0000u;
    union { _Float16 h[2]; unsigned int u; } r;
    r.h[0] = (_Float16)a.f;
    r.h[1] = (_Float16)b.f;
    return r.u;
}

__device__ __forceinline__ uint4 cvt8_bf16_to_f16(uint4 v) {
    uint4 r;
    r.x = cvt2_bf16_to_f16(v.x);
    r.y = cvt2_bf16_to_f16(v.y);
    r.z = cvt2_bf16_to_f16(v.z);
    r.w = cvt2_bf16_to_f16(v.w);
    return r;
}

__device__ __forceinline__ float dot2(unsigned int a, unsigned int b, float c) {
    union { unsigned int u; half2_t h; } ua, ub;
    ua.u = a; ub.u = b;
#if defined(__HIP_DEVICE_COMPILE__) && __has_builtin(__builtin_amdgcn_fdot2)
    return __builtin_amdgcn_fdot2(ua.h, ub.h, c, false);
#else
    return c + (float)ua.h.x * (float)ub.h.x + (float)ua.h.y * (float)ub.h.y;
#endif
}

// tanh(x) = 1 - 2/(exp(2x)+1); finite for all finite x.
__device__ __forceinline__ float tanh_fast(float x) {
#if defined(__HIP_DEVICE_COMPILE__) && __has_builtin(__builtin_amdgcn_exp2f)
    float e = __builtin_amdgcn_exp2f(x * 2.885390081777927f);  // exp(2x)
#else
    float e = exp2f(x * 2.885390081777927f);
#endif
    return 1.f - 2.f / (e + 1.f);
}

__device__ __forceinline__ unsigned int pk2(float a, float b) {
    union { fp16x2_t h; unsigned int u; } r;
    r.h = __builtin_amdgcn_cvt_pkrtz(a, b);  // v_cvt_pkrtz_f16_f32
    return r.u;
}

// LDS-only workgroup barrier (no vmcnt drain).
__device__ __forceinline__ void wg_barrier_lds() {
    __asm__ volatile("s_waitcnt lgkmcnt(0)\n\ts_barrier" ::: "memory");
}

// xw swizzle: swap j bit-pairs [5:4]<->[3:2] so lane (w,q) gets its 16
// values (mi,r) contiguous: jc = w*64 + q*16 + mi*4 + r.
__device__ __forceinline__ int swz_j(int j) {
    return (j & 0xC3) | ((j & 0x30) >> 2) | ((j & 0x0C) << 2);
}

// ---- dtype detection (bf16 weights have exponent field <= 122) -----------
__global__ void detect_dtype(const unsigned short* __restrict__ w, int* __restrict__ flag) {
    if (threadIdx.x == 0 && blockIdx.x == 0) {
        int f = 0;
        for (int i = 0; i < 512; ++i) {
            unsigned e = (w[i] >> 7) & 0xFF;
            if (e >= 127) f = 1;
        }
        *flag = f;
    }
}

// ---- prep: weights -> f16, bias sums -> f32, zero carries ----------------
__global__ void prep_w(const void* __restrict__ wih0, const void* __restrict__ whh0,
                       const void* __restrict__ bih0, const void* __restrict__ bhh0,
                       const void* __restrict__ wih1, const void* __restrict__ whh1,
                       const void* __restrict__ bih1, const void* __restrict__ bhh1,
                       _Float16* __restrict__ owih0, _Float16* __restrict__ owhh0,
                       _Float16* __restrict__ owih1, _Float16* __restrict__ owhh1,
                       float* __restrict__ obias0, float* __restrict__ obias1,
                       uint4* __restrict__ carries, const int* __restrict__ flag) {
    const bool f32 = (*flag != 0);
    int i = blockIdx.x * 256 + threadIdx.x;
    auto rd = [&](const void* p, int idx) -> float {
        return f32 ? ((const float*)p)[idx] : bf2f(((const unsigned short*)p)[idx]);
    };
    if (i < H_ * D_) owih0[i] = (_Float16)rd(wih0, i);
    if (i < H_ * H_) {
        owhh0[i] = (_Float16)rd(whh0, i);
        owih1[i] = (_Float16)rd(wih1, i);
        owhh1[i] = (_Float16)rd(whh1, i);
    }
    if (i < H_) {
        obias0[i] = rd(bih0, i) + rd(bhh0, i);
        obias1[i] = rd(bih1, i) + rd(bhh1, i);
    }
    if (i < (2 * B_ * H_) / 8) carries[i] = uint4{0, 0, 0, 0};
}

// ---- chunk projection (dot2): xw[m][swz(j)] = A_row(m).W[j] + bias[j] ----
template <int K, bool SRCX>
__global__ __launch_bounds__(256, 1) void proj_chunk(const void* __restrict__ A,
                                                     const _Float16* __restrict__ W,
                                                     const float* __restrict__ bias,
                                                     _Float16* __restrict__ outx,
                                                     const int* __restrict__ flag,
                                                     int t0, int Tc) {
    constexpr int KW = K / 8;
    const int j = threadIdx.x;
    const int jc = swz_j(j);          // swizzled output column
    const long m0 = (long)blockIdx.x * 16;
    const bool f32 = SRCX && (*flag != 0);

    long arow0;
    if (SRCX) {
        long b = m0 / Tc;
        long tc0 = m0 - b * Tc;
        arow0 = (b * T_ + t0 + tc0) * (long)K;
    } else {
        arow0 = m0 * (long)K;
    }

    uint4 w[KW];
    const uint4* wp = (const uint4*)(W + (long)j * K);
#pragma unroll
    for (int i = 0; i < KW; ++i) w[i] = wp[i];

    __shared__ uint4 xt[16 * KW];
    for (int i = threadIdx.x; i < 16 * KW; i += 256) {
        int r = i / KW, c = i % KW;
        long off = arow0 + (long)r * K + (long)c * 8;
        if (SRCX) {
            if (f32) {
                const float* s = (const float*)A + off;
                union { _Float16 h[8]; uint4 u; } r8;
#pragma unroll
                for (int qq = 0; qq < 8; ++qq) r8.h[qq] = (_Float16)s[qq];
                xt[i] = r8.u;
            } else {
                xt[i] = cvt8_bf16_to_f16(*(const uint4*)((const unsigned short*)A + off));
            }
        } else {
            xt[i] = *(const uint4*)((const _Float16*)A + off);
        }
    }
    __syncthreads();

    const float bb = bias[j];
#pragma unroll 1
    for (int r = 0; r < 16; ++r) {
        const uint4* xr = xt + r * KW;
        float a0 = 0.f, a1 = 0.f, a2 = 0.f, a3 = 0.f;
#pragma unroll
        for (int i = 0; i < KW; ++i) {
            uint4 h = xr[i];
            uint4 ww = w[i];
            a0 = dot2(ww.x, h.x, a0);
            a1 = dot2(ww.y, h.y, a1);
            a2 = dot2(ww.z, h.z, a2);
            a3 = dot2(ww.w, h.w, a3);
        }
        outx[(m0 + r) * H_ + jc] = (_Float16)(((a0 + a1) + (a2 + a3)) + bb);
    }
}

// ---- fused MFMA scan ------------------------------------------------------
// grid 8: blocks 0-3 layer0 (16-batch groups), 4-7 layer1.
// Wave w owns j in [w*64, w*64+64). A-frag lane(m=L&15,k=(L>>4)*8+r);
// B-frag lane(n=L&15,k=(L>>4)*8+r); D lane(n=L&15,j=(L>>4)*4+reg).
// h in LDS [k>>3][n][k&7] f16 double-buffered; xw 2-step reg lookahead.
__global__ __launch_bounds__(256, 1) void scan_mfma(
    const _Float16* __restrict__ xw0, const _Float16* __restrict__ whh0,
    _Float16* __restrict__ carry0, _Float16* __restrict__ hout0, int act0,
    const _Float16* __restrict__ xw1, const _Float16* __restrict__ whh1,
    _Float16* __restrict__ carry1, _Float16* __restrict__ hout1, int act1,
    int Tc) {
    const int layer = blockIdx.x >> 2;
    const int g = blockIdx.x & 3;
    if (layer == 0 && !act0) return;
    if (layer == 1 && !act1) return;
    const _Float16* xw  = layer ? xw1  : xw0;
    const _Float16* whh = layer ? whh1 : whh0;
    _Float16* carry = layer ? carry1 : carry0;
    _Float16* hout  = layer ? hout1 : hout0;

    const int tid = threadIdx.x;
    const int w = tid >> 6, L = tid & 63;
    const int q = L >> 4, n = L & 15;
    const int j0q = q * 4;

    // W_hh A-fragments -> VGPRs (4 M-tiles x 8 K-tiles x 8 f16 = 128 VGPRs)
    half8_t a[4][8];
#pragma unroll
    for (int mi = 0; mi < 4; ++mi) {
        int m = (w * 4 + mi) * 16 + n;
#pragma unroll
        for (int kt = 0; kt < 8; ++kt)
            a[mi][kt] = *(const half8_t*)(whh + m * H_ + kt * 32 + q * 8);
    }

    __shared__ _Float16 hB[2][32 * 16 * 8];  // [oct=k>>3][n][k&7]
    for (int nn = 0; nn < NB; ++nn)
        hB[0][((tid >> 3) * 16 + nn) * 8 + (tid & 7)] = carry[(g * NB + nn) * H_ + tid];

    // swizzled xw: lane (w,q) reads 16 contiguous f16 at col w*64+q*16
    const _Float16* xp = xw + (long)(g * NB + n) * Tc * H_ + w * 64 + q * 16;
    _Float16* hop = hout + (long)(g * NB + n) * Tc * H_;  // unswizzled [row][j]

    uint4 xwreg[2][2];  // [set][16 f16]
    xwreg[0][0] = *(const uint4*)(xp);
    xwreg[0][1] = *(const uint4*)(xp + 8);
    xwreg[1][0] = *(const uint4*)(xp + (long)H_);
    xwreg[1][1] = *(const uint4*)(xp + (long)H_ + 8);

    __syncthreads();

    auto step = [&](int t, int s) {
        // B fragments: 8 distributed ds_read_b128
        const _Float16* hb = hB[t & 1];
        half8_t bf[8];
#pragma unroll
        for (int kt = 0; kt < 8; ++kt)
            bf[kt] = *(const half8_t*)(hb + ((kt * 4 + q) * 16 + n) * 8);

        // 8 independent chains of depth 4
        f32x4_t acc[4][2];
#pragma unroll
        for (int mi = 0; mi < 4; ++mi) {
            acc[mi][0] = (f32x4_t){0.f, 0.f, 0.f, 0.f};
            acc[mi][1] = (f32x4_t){0.f, 0.f, 0.f, 0.f};
        }
#pragma unroll
        for (int kt = 0; kt < 8; kt += 2) {
#pragma unroll
            for (int mi = 0; mi < 4; ++mi) {
                acc[mi][0] = __builtin_amdgcn_mfma_f32_16x16x32_f16(a[mi][kt],     bf[kt],     acc[mi][0], 0, 0, 0);
                acc[mi][1] = __builtin_amdgcn_mfma_f32_16x16x32_f16(a[mi][kt + 1], bf[kt + 1], acc[mi][1], 0, 0, 0);
            }
        }

        // activation + h write (consumes xwreg[s])
        _Float16* hw = hB[(t + 1) & 1];
        const _Float16* xh = (const _Float16*)&xwreg[s][0];  // 16 f16: (mi,r)
#pragma unroll
        for (int mi = 0; mi < 4; ++mi) {
            float v0 = tanh_fast(acc[mi][0][0] + acc[mi][1][0] + (float)xh[mi * 4 + 0]);
            float v1 = tanh_fast(acc[mi][0][1] + acc[mi][1][1] + (float)xh[mi * 4 + 1]);
            float v2 = tanh_fast(acc[mi][0][2] + acc[mi][1][2] + (float)xh[mi * 4 + 2]);
            float v3 = tanh_fast(acc[mi][0][3] + acc[mi][1][3] + (float)xh[mi * 4 + 3]);
            uint2 pk = uint2{pk2(v0, v1), pk2(v2, v3)};
            int j0 = (w * 4 + mi) * 16 + j0q;
            *(uint2*)(hw + ((j0 >> 3) * 16 + n) * 8 + (j0 & 7)) = pk;
            *(uint2*)(hop + (long)t * H_ + j0) = pk;  // stays in flight
        }

        // reload this set with t+2 (WAR only -> no wait; ~2 steps of slack)
        int tn = (t + 2 < Tc) ? t + 2 : t;
        xwreg[s][0] = *(const uint4*)(xp + (long)tn * H_);
        xwreg[s][1] = *(const uint4*)(xp + (long)tn * H_ + 8);

        wg_barrier_lds();
    };

    for (int t = 0; t < Tc; t += 2) {
        step(t, 0);
        step(t + 1, 1);
    }

    const _Float16* hf = hB[Tc & 1];
    for (int nn = 0; nn < NB; ++nn)
        carry[(g * NB + nn) * H_ + tid] = hf[((tid >> 3) * 16 + nn) * 8 + (tid & 7)];
}

// ---- transpose: ho1[b][t][j] f16 -> out[b][j][t0+t] (bf16|f32) -----------
#define TSTR 68
__global__ __launch_bounds__(256) void transpose_out(const _Float16* __restrict__ hsrc,
                                                     void* __restrict__ out,
                                                     const int* __restrict__ flag,
                                                     int t0, int Tc) {
    const bool f32o = (*flag != 0);
    const int ntt = Tc >> 6;
    int bx = blockIdx.x;
    int b  = bx / (ntt * 4);
    int r  = bx % (ntt * 4);
    int tt = r >> 2, jt = r & 3;
    __shared__ _Float16 tile[64 * TSTR];
    int tid = threadIdx.x;
#pragma unroll
    for (int p = 0; p < 2; ++p) {
        int lin = p * 256 + tid;
        int t = lin >> 3, c = lin & 7;
        uint4 v = *(const uint4*)(hsrc + ((long)b * Tc + tt * 64 + t) * H_ + jt * 64 + c * 8);
        *(uint2*)(tile + t * TSTR + c * 8)     = uint2{v.x, v.y};
        *(uint2*)(tile + t * TSTR + c * 8 + 4) = uint2{v.z, v.w};
    }
    __syncthreads();
    int t = tid & 63, jl = tid >> 6;
#pragma unroll
    for (int p = 0; p < 16; ++p) {
        int j = p * 4 + jl;
        float v = (float)tile[t * TSTR + j];
        long oi = ((long)b * H_ + jt * 64 + j) * T_ + t0 + tt * 64 + t;
        if (f32o) ((float*)out)[oi] = v;
        else      ((__hip_bfloat16*)out)[oi] = __float2bfloat16(v);
    }
}

// ---------------------------------------------------------------------------
extern "C" void kernel_launch(void* const* d_in, const int* in_sizes, int n_in,
                              void* d_out, int out_size, void* d_ws, size_t ws_size,
                              hipStream_t stream) {
    const void* x    = d_in[0];
    const void* wih0 = d_in[1];
    const void* whh0 = d_in[2];
    const void* bih0 = d_in[3];
    const void* bhh0 = d_in[4];
    const void* wih1 = d_in[5];
    const void* whh1 = d_in[6];
    const void* bih1 = d_in[7];
    const void* bhh1 = d_in[8];
    (void)in_sizes; (void)n_in; (void)out_size;

    char* ws = (char*)d_ws;
    size_t off = 0;
    auto alloc = [&](size_t bytes) -> void* {
        void* p = ws + off;
        off += (bytes + 255) & ~(size_t)255;
        return p;
    };

    int*      flag    = (int*)alloc(256);
    _Float16* wih0_16 = (_Float16*)alloc((size_t)H_ * D_ * 2);
    _Float16* whh0_16 = (_Float16*)alloc((size_t)H_ * H_ * 2);
    _Float16* wih1_16 = (_Float16*)alloc((size_t)H_ * H_ * 2);
    _Float16* whh1_16 = (_Float16*)alloc((size_t)H_ * H_ * 2);
    float*    bias0   = (float*)alloc(H_ * 4);
    float*    bias1   = (float*)alloc(H_ * 4);
    _Float16* carry0  = (_Float16*)alloc((size_t)B_ * H_ * 2);
    _Float16* carry1  = (_Float16*)alloc((size_t)B_ * H_ * 2);
    size_t fixed = off;

    int Tc = 256;
    while (Tc > 32 && fixed + 4 * ((size_t)B_ * Tc * H_ * 2 + 256) > ws_size) Tc >>= 1;
    _Float16* xw0c = (_Float16*)alloc((size_t)B_ * Tc * H_ * 2);
    _Float16* xw1c = (_Float16*)alloc((size_t)B_ * Tc * H_ * 2);
    _Float16* hbuf[2];
    hbuf[0] = (_Float16*)alloc((size_t)B_ * Tc * H_ * 2);
    hbuf[1] = (_Float16*)alloc((size_t)B_ * Tc * H_ * 2);

    detect_dtype<<<1, 64, 0, stream>>>((const unsigned short*)whh0, flag);
    prep_w<<<(H_ * H_ + 255) / 256, 256, 0, stream>>>(
        wih0, whh0, bih0, bhh0, wih1, whh1, bih1, bhh1,
        wih0_16, whh0_16, wih1_16, whh1_16, bias0, bias1, (uint4*)carry0, flag);

    const int nproj = (B_ * Tc) / 16;
    const int nc = T_ / Tc;
    const int ntrans = B_ * (Tc / 64) * 4;
    // stage s: proj0(s) ; proj1(s-1) ; [scan0(s) || scan1(s-1)] ; transpose(s-1)
    for (int s = 0; s <= nc; ++s) {
        if (s < nc)
            proj_chunk<D_, true><<<nproj, 256, 0, stream>>>(x, wih0_16, bias0, xw0c, flag, s * Tc, Tc);
        if (s >= 1)
            proj_chunk<H_, false><<<nproj, 256, 0, stream>>>(hbuf[(s - 1) & 1], wih1_16, bias1, xw1c, flag, 0, Tc);
        scan_mfma<<<8, 256, 0, stream>>>(
            xw0c, whh0_16, carry0, hbuf[s & 1], (s < nc) ? 1 : 0,
            xw1c, whh1_16, carry1, hbuf[(s - 1) & 1], (s >= 1) ? 1 : 0, Tc);
        if (s >= 1)
            transpose_out<<<ntrans, 256, 0, stream>>>(hbuf[(s - 1) & 1], d_out, flag, (s - 1) * Tc, Tc);
    }
}